// Round 7
// baseline (99.149 us; speedup 1.0000x reference)
//
#include <hip/hip_runtime.h>
#include <math.h>

// Chamfer p-norm loss (P=5), B=8, N=M=4096, C=3.
// R15: eliminate the exact-index RESCAN via inline j-tracking.
// Evidence: R10(4w,LDS)~42, R11(8w,LDS)=40.2, R12(8w,L1-table)=42.2,
// R14(4w,table+reg-dbuf)~38 — four hot-loop read structures, same ~40us,
// VALU-busy ~20us in all. Hot-loop read path and prefetch distance are
// proven irrelevant; the constant across all variants is the rescan:
// 96 per-lane DIVERGENT gathers/thread (bg differs per lane -> each wave
// load spans ~32 cache lines -> ~16-32 TA cycles/instr; 16 waves/CU x 96
// x ~20cyc ~ 15-20us of TA serialization). Change: track (best, bj) per
// pair during the scan: mp=fmin(s.x,s.y); jp=2p+(s.x<=s.y?0:1); strict-<
// update. Tie semantics: strict < keeps the earliest pair attaining the
// final min; within pair, even index preferred on tie -> smallest j in
// split achieving the min == old earliest-group + descending-rescan
// result. Score chain bit-identical -> same key bits -> absmax 0.0.
// Cost ~+3.5 VALU/pair/qk (+~5us); removes all divergent gathers.
// R10/R11 lessons kept: NO __threadfence (per-wave L2 wb/inv = ~100us);
// __syncthreads' mandatory vmcnt(0) drains atomicMax before tid0's counter
// bump; consumers read tab/psum via AGENT-scope atomic loads (sc bypass).
// mktab->fused visibility = kernel boundary (R8-proven). Counter init in
// poisoned ws: CANARY word (never written) holds the fill value; "last"
// test old==canary+(n-1); finalizer restores counters.
// Keys: complemented (score<<32|j), atomicMax; poison/zeros < any real key.

#define BQ      256
#define QPT     4             // queries per thread
#define SPLITS  16
#define CH      256           // refs per split-block
#define GS      8             // refs per tracked group
#define NG      (CH / GS)     // 32 groups
#define BIGOFF  64.0f         // folds into h: scores stay in (64-|q|^2/2, ~200) > 0
#define NQTOT   65536         // 2 dirs * 8 batches * 4096 queries
#define NTILE   64            // query tiles of 1024
#define TILEQ   1024          // queries per tile (BQ * QPT)

typedef float f32x2 __attribute__((ext_vector_type(2)));
typedef float f32x4 __attribute__((ext_vector_type(4)));

static __device__ __forceinline__ f32x2 mk2(float s) { f32x2 v; v.x = s; v.y = s; return v; }
static __device__ __forceinline__ f32x2 fma2(f32x2 a, f32x2 b, f32x2 c) {
    return __builtin_elementwise_fma(a, b, c);
}
__device__ __forceinline__ unsigned int float_ord(float f) {
    unsigned int u = __float_as_uint(f);
    return (u & 0x80000000u) ? ~u : (u | 0x80000000u);
}

// ws layout (fast path):
//   [0,64)      legacy acc area (fallback path only)
//   [128,132)   CANARY u32 — never written; holds the uniform fill value
//   [192,196)   gcnt u32  — global tile-completion counter (starts at canary)
//   [256,512)   tcnt[64] u32 — per-tile split counters (start at canary)
//   [1024,1280) psum[64] f32 — per-tile partial sums
//   [4096, 4096+512K) tab u64[NQTOT] — complemented (score|j) keys, atomicMax
//   [1M, 2M)    tbl f32x4[2 dirs][8 b][2048 pairs][2] — pair-layout ref table
#define WS_ACC    0
#define WS_CANARY 128
#define WS_GCNT   192
#define WS_TCNT   256
#define WS_PSUM   1024
#define WS_TAB    4096
#define WS_TBL    1048576

// ---- phase 0: build the pair-layout (x,x',y,y')(z,z',h,h') ref table.
// 32768 pairs total = 2 dirs * 8 b * 2048 pairs. h chain bit-identical to
// the scan's. Kernel-end release makes it visible to the scan (R8 pattern).
__global__ __launch_bounds__(BQ) void chamfer_mktab(
    const float* __restrict__ x, const float* __restrict__ y,
    float4* __restrict__ tbl)
{
    const int t   = blockIdx.x * BQ + threadIdx.x;   // 0..32767
    const int dir = t >> 14;
    const int b   = (t >> 11) & 7;
    const int pr  = t & 2047;
    const float* R = (dir == 0 ? y : x) + (size_t)b * 4096 * 3;
    const float* rp = R + (size_t)(2 * pr) * 3;
    const float f0 = rp[0], f1 = rp[1], f2 = rp[2];
    const float f3 = rp[3], f4 = rp[4], f5 = rp[5];
    const float h0 = fmaf(0.5f * f0, f0, fmaf(0.5f * f1, f1, fmaf(0.5f * f2, f2, BIGOFF)));
    const float h1 = fmaf(0.5f * f3, f3, fmaf(0.5f * f4, f4, fmaf(0.5f * f5, f5, BIGOFF)));
    const size_t o = ((size_t)(dir * 8 + b) * 2048 + pr) * 2;
    tbl[o]     = make_float4(f0, f3, f1, f4);
    tbl[o + 1] = make_float4(f2, f5, h0, h1);
}

// compute one GS-ref group (4 pairs) from a register buffer, tracking the
// exact smallest-j-at-min inline; bit-identical score chain.
#define COMPUTE_GROUP(BUF, G)                                              \
  {                                                                        \
    _Pragma("unroll")                                                      \
    for (int k4 = 0; k4 < 4; ++k4) {                                       \
      const f32x4 a = BUF[2 * k4];          /* rx0,rx1,ry0,ry1 */          \
      const f32x4 c = BUF[2 * k4 + 1];      /* rz0,rz1,h0,h1  */           \
      const f32x2 rx = __builtin_shufflevector(a, a, 0, 1);                \
      const f32x2 ry = __builtin_shufflevector(a, a, 2, 3);                \
      const f32x2 rz = __builtin_shufflevector(c, c, 0, 1);                \
      const f32x2 h2 = __builtin_shufflevector(c, c, 2, 3);                \
      const int jbase = ((G) * 4 + k4) * 2;                                \
      _Pragma("unroll")                                                    \
      for (int qk = 0; qk < QPT; ++qk) {                                   \
        const f32x2 s = fma2(nqx[qk], rx,                                  \
                        fma2(nqy[qk], ry, fma2(nqz[qk], rz, h2)));         \
        const float mp = fminf(s.x, s.y);                                  \
        const int   jp = jbase + ((s.x <= s.y) ? 0 : 1); /* tie->even */   \
        const bool  cc = mp < best[qk];     /* strict <: earliest pair */  \
        best[qk] = cc ? mp : best[qk];                                     \
        bj[qk]   = cc ? jp : bj[qk];                                       \
      }                                                                    \
    }                                                                      \
  }

// ---- fused scan + per-tile gather + finalize:
// grid = 64 query-tiles (1024 q each) x 16 ref-splits = 1024 blocks
__global__ __launch_bounds__(BQ, 4) void chamfer_fused_r15(
    const float* __restrict__ x, const float* __restrict__ y,
    const f32x4* __restrict__ tbl,
    unsigned long long* __restrict__ tab,
    unsigned int* __restrict__ tcnt, unsigned int* __restrict__ gcnt,
    const unsigned int* __restrict__ canary_p,
    float* __restrict__ psum, float* __restrict__ out)
{
    __shared__ float red[4];
    __shared__ int s_flag;

    const int bid   = blockIdx.x;
    const int split = bid & (SPLITS - 1);
    const int tq    = bid >> 4;          // 0..63 = dir*32 + b*4 + t4
    const int dir   = tq >> 5;
    const int b     = (tq >> 2) & 7;
    const int t4    = tq & 3;

    const unsigned int canary = *canary_p;  // uniform fill value (0xAA.. or 0)

    const float* Q; const float* R;
    if (dir == 0) { Q = x + (size_t)b * 4096 * 3; R = y + (size_t)b * 4096 * 3; }
    else          { Q = y + (size_t)b * 4096 * 3; R = x + (size_t)b * 4096 * 3; }

    const int tid = threadIdx.x;

    // this block's split region of the table: 128 pairs = 256 f32x4s
    const f32x4* __restrict__ tb =
        tbl + ((size_t)(dir * 8 + b) * 4096 + (size_t)split * 256);

    // 4 scalar queries per thread, kept ONLY as negated pk splats.
    f32x2 nqx[QPT], nqy[QPT], nqz[QPT];
    #pragma unroll
    for (int qk = 0; qk < QPT; ++qk) {
        const int ql = t4 * TILEQ + qk * 256 + tid;
        nqx[qk] = mk2(-Q[ql * 3 + 0]);
        nqy[qk] = mk2(-Q[ql * 3 + 1]);
        nqz[qk] = mk2(-Q[ql * 3 + 2]);
    }

    float best[QPT]; int bj[QPT];
    #pragma unroll
    for (int qk = 0; qk < QPT; ++qk) { best[qk] = 3.4e38f; bj[qk] = 0; }

    // ---- register double-buffered group pipeline:
    // prefetch group g+1 while computing g. Final prefetch wraps to group 0
    // ((g+2)&(NG-1)) — in-bounds, value never consumed.
    f32x4 bufA[8], bufB[8];
    #pragma unroll
    for (int i = 0; i < 8; ++i) bufA[i] = tb[i];

    #pragma unroll 1
    for (int g = 0; g < NG; g += 2) {
        #pragma unroll
        for (int i = 0; i < 8; ++i) bufB[i] = tb[(g + 1) * 8 + i];
        COMPUTE_GROUP(bufA, g)
        const int gpre = (g + 2) & (NG - 1);   // wraps to 0 on last iter
        #pragma unroll
        for (int i = 0; i < 8; ++i) bufA[i] = tb[gpre * 8 + i];
        COMPUTE_GROUP(bufB, g + 1)
    }

    // ---- publish candidates: NO rescan — bj tracked inline.
    #pragma unroll
    for (int qk = 0; qk < QPT; ++qk) {
        const size_t qidx = (size_t)tq * TILEQ + qk * 256 + tid;
        const unsigned int jabs = (unsigned int)(split * CH + bj[qk]);
        // complemented key: max(~packed) == min(packed); 0xAA poison and
        // fresh zeros are both < any real key -> no init required.
        const unsigned long long key =
            ~(((unsigned long long)__float_as_uint(best[qk]) << 32) | jabs);
        atomicMax(&tab[qidx], key);   // fire-and-forget (return unused)
    }

    // ---- per-tile completion handshake: 16th split-block gathers the tile.
    // NO __threadfence (R9 lesson: per-wave buffer_wbl2/inv = ~100us).
    // __syncthreads' compiler-mandated s_waitcnt vmcnt(0) drains every
    // wave's atomicMax to the coherent point before tid0's counter bump.
    __syncthreads();
    if (tid == 0) {
        const unsigned int old = atomicAdd(&tcnt[tq], 1u);
        s_flag = (old == canary + (SPLITS - 1));
    }
    __syncthreads();
    if (!s_flag) return;

    // ---- gather this tile's 1024 queries (4/thread). tab MUST be read with
    // AGENT-scope atomic loads (sc cache-bypass): local L2 may hold stale
    // poison lines; atomicMax updated the coherent point only (R4 lesson).
    float sthr = 0.0f;
    #pragma unroll
    for (int k = 0; k < QPT; ++k) {
        const int gq = tq * TILEQ + k * 256 + tid;
        const int q  = t4 * TILEQ + k * 256 + tid;
        const unsigned long long w =
            ~__hip_atomic_load(&tab[gq], __ATOMIC_RELAXED, __HIP_MEMORY_SCOPE_AGENT);
        const int j = (int)(unsigned int)w;
        const float dx = Q[q * 3 + 0] - R[(size_t)j * 3 + 0];
        const float dy = Q[q * 3 + 1] - R[(size_t)j * 3 + 1];
        const float dz = Q[q * 3 + 2] - R[(size_t)j * 3 + 2];
        const float ax = fabsf(dx), ay = fabsf(dy), az = fabsf(dz);
        const float ax2 = ax * ax, ay2 = ay * ay, az2 = az * az;
        sthr += ax2 * ax2 * ax + ay2 * ay2 * ay + az2 * az2 * az;
    }
    #pragma unroll
    for (int off = 32; off > 0; off >>= 1) sthr += __shfl_down(sthr, off, 64);
    const int wid = tid >> 6, lane = tid & 63;
    if (lane == 0) red[wid] = sthr;
    __syncthreads();

    if (tid == 0) {
        __hip_atomic_store(&psum[tq], red[0] + red[1] + red[2] + red[3],
                           __ATOMIC_RELAXED, __HIP_MEMORY_SCOPE_AGENT);
        // order psum store before gcnt bump: drain to coherent point (1 instr,
        // single thread — NOT a threadfence, no L2 writeback).
        asm volatile("s_waitcnt vmcnt(0)" ::: "memory");
        const unsigned int old = atomicAdd(gcnt, 1u);
        s_flag = (old == canary + (NTILE - 1));
    }
    __syncthreads();
    if (!s_flag) return;

    // ---- globally-last tile: finalize. x^0.2 via exp2/log2 (rel err ~1e-5).
    // psum read via AGENT-scope bypass loads: counter RMW return proved all
    // writers' stores performed at the coherent point before ours.
    if (tid < 64) {
        float v = 0.0f;
        if (tid < 16) {
            const int fb = tid >> 1, fdir = tid & 1;  // slot = b*2+dir
            float a = 0.0f;
            #pragma unroll
            for (int t = 0; t < 4; ++t)
                a += __hip_atomic_load(&psum[fdir * 32 + fb * 4 + t],
                                       __ATOMIC_RELAXED, __HIP_MEMORY_SCOPE_AGENT);
            v = exp2f(0.2f * log2f(a));
        }
        #pragma unroll
        for (int off = 8; off > 0; off >>= 1) v += __shfl_down(v, off, 64);
        if (tid == 0) out[0] = v * 0.125f;            // mean over B=8
    }
    // restore counters to the canary value so a non-repoisoned rerun is
    // still correct (tab is idempotent under atomicMax with same inputs).
    if (tid < NTILE)
        __hip_atomic_store(&tcnt[tid], canary, __ATOMIC_RELAXED, __HIP_MEMORY_SCOPE_AGENT);
    if (tid == 0)
        __hip_atomic_store(gcnt, canary, __ATOMIC_RELAXED, __HIP_MEMORY_SCOPE_AGENT);
}

// ================= round-2 proven fallback (generic sizes) =================
__global__ __launch_bounds__(BQ) void chamfer_nn_split_kernel(
    const float* __restrict__ x, const float* __restrict__ y,
    unsigned long long* __restrict__ packed, int N, int M)
{
    __shared__ float4 sref[1024];
    const int bid = blockIdx.x, split = bid & 3, qb = bid >> 2;
    const int tile = qb & 15, dir = (qb >> 4) & 1, b = qb >> 5;
    const float* Q; const float* R;
    if (dir == 0) { Q = x + (size_t)b * N * 3; R = y + (size_t)b * M * 3; }
    else          { Q = y + (size_t)b * M * 3; R = x + (size_t)b * N * 3; }
    const int tid = threadIdx.x, q = tile * BQ + tid, base = split * 1024;
    for (int j = tid; j < 1024; j += BQ) {
        const float rx = R[(size_t)(base + j) * 3 + 0];
        const float ry = R[(size_t)(base + j) * 3 + 1];
        const float rz = R[(size_t)(base + j) * 3 + 2];
        sref[j] = make_float4(rx, ry, rz, 0.5f * (rx * rx + ry * ry + rz * rz));
    }
    __syncthreads();
    const float qx = Q[q * 3 + 0], qy = Q[q * 3 + 1], qz = Q[q * 3 + 2];
    float best = 3.4e38f; int bestj = base;
    #pragma unroll 8
    for (int j = 0; j < 1024; ++j) {
        const float4 r = sref[j];
        float t = __fmaf_rn(-qx, r.x, r.w);
        t = __fmaf_rn(-qy, r.y, t);
        t = __fmaf_rn(-qz, r.z, t);
        const bool c = t < best;
        best = c ? t : best; bestj = c ? (base + j) : bestj;
    }
    const size_t idx = ((size_t)dir * 8 + b) * (size_t)N + q;
    atomicMin(&packed[idx], ((unsigned long long)float_ord(best) << 32) | (unsigned int)bestj);
}

__global__ __launch_bounds__(BQ) void chamfer_gather_kernel(
    const float* __restrict__ x, const float* __restrict__ y,
    const unsigned long long* __restrict__ packed,
    float* __restrict__ acc, int N, int M)
{
    __shared__ float red[4];
    const int tid = threadIdx.x;
    const size_t gq = (size_t)blockIdx.x * BQ + tid;
    const int dir = (int)(gq / ((size_t)8 * N));
    const size_t rem = gq - (size_t)dir * 8 * N;
    const int b = (int)(rem / N), q = (int)(rem - (size_t)b * N);
    const float* Q; const float* R;
    if (dir == 0) { Q = x + (size_t)b * N * 3; R = y + (size_t)b * M * 3; }
    else          { Q = y + (size_t)b * M * 3; R = x + (size_t)b * N * 3; }
    const int j = (int)(unsigned int)packed[gq];
    const float dx = Q[q * 3 + 0] - R[(size_t)j * 3 + 0];
    const float dy = Q[q * 3 + 1] - R[(size_t)j * 3 + 1];
    const float dz = Q[q * 3 + 2] - R[(size_t)j * 3 + 2];
    const float ax = fabsf(dx), ay = fabsf(dy), az = fabsf(dz);
    const float ax2 = ax * ax, ay2 = ay * ay, az2 = az * az;
    float s = ax2 * ax2 * ax + ay2 * ay2 * ay + az2 * az2 * az;
    #pragma unroll
    for (int off = 32; off > 0; off >>= 1) s += __shfl_down(s, off, 64);
    const int wid = tid >> 6, lane = tid & 63;
    if (lane == 0) red[wid] = s;
    __syncthreads();
    if (tid == 0) atomicAdd(&acc[b * 2 + dir], red[0] + red[1] + red[2] + red[3]);
}

__global__ void chamfer_finalize_kernel(const float* __restrict__ acc,
                                        float* __restrict__ out)
{
    if (threadIdx.x == 0 && blockIdx.x == 0) {
        float total = 0.0f;
        #pragma unroll
        for (int i = 0; i < 16; ++i) total += powf(acc[i], 0.2f);
        *out = total * 0.125f;
    }
}

extern "C" void kernel_launch(void* const* d_in, const int* in_sizes, int n_in,
                              void* d_out, int out_size, void* d_ws, size_t ws_size,
                              hipStream_t stream)
{
    const float* x = (const float*)d_in[0];
    const float* y = (const float*)d_in[1];
    float* out = (float*)d_out;
    const int N = in_sizes[0] / 24;  // B=8, C=3
    const int M = in_sizes[1] / 24;

    const size_t needed = WS_TBL + (1u << 20);  // table ends at 2MB

    if (N == 4096 && M == 4096 && ws_size >= needed) {
        unsigned char* ws = (unsigned char*)d_ws;
        unsigned long long* tab = (unsigned long long*)(ws + WS_TAB);
        unsigned int* tcnt = (unsigned int*)(ws + WS_TCNT);
        unsigned int* gcnt = (unsigned int*)(ws + WS_GCNT);
        const unsigned int* canary = (const unsigned int*)(ws + WS_CANARY);
        float* psum = (float*)(ws + WS_PSUM);
        chamfer_mktab<<<32768 / BQ, BQ, 0, stream>>>(x, y, (float4*)(ws + WS_TBL));
        chamfer_fused_r15<<<NTILE * SPLITS, BQ, 0, stream>>>(
            x, y, (const f32x4*)(ws + WS_TBL), tab, tcnt, gcnt, canary, psum, out);
    } else {
        // round-2 proven path
        unsigned char* ws = (unsigned char*)d_ws;
        float* acc = (float*)ws;
        unsigned long long* ptab = (unsigned long long*)(ws + 4096);
        const size_t nQ = (size_t)2 * 8 * N;
        hipMemsetAsync(acc, 0, 64, stream);
        hipMemsetAsync(ptab, 0xFF, nQ * 8, stream);
        chamfer_nn_split_kernel<<<(int)(nQ / BQ) * 4, BQ, 0, stream>>>(x, y, ptab, N, M);
        chamfer_gather_kernel<<<(int)(nQ / BQ), BQ, 0, stream>>>(x, y, ptab, acc, N, M);
        chamfer_finalize_kernel<<<1, 64, 0, stream>>>(acc, out);
    }
}

// Round 8
// 96.591 us; speedup vs baseline: 1.0265x; 1.0265x over previous
//
#include <hip/hip_runtime.h>
#include <math.h>

// Chamfer p-norm loss (P=5), B=8, N=M=4096, C=3.
// R16: spread the synchronized atomic storm. Decomposition from R12/R14/R15
// counters: scan = VALU-busy (19-30us, tracks instr count) + CONSTANT
// ~18-20us stall untouched by read-path (LDS/L1/SMEM), occupancy, or
// prefetch changes. The one synchronized, identical-in-all-variants
// component: all 4096 waves finish together, then fire 1M u64 atomicMax
// (16 same-address contenders/qidx) into a barrier-mandated vmcnt(0) —
// ~13us of L2 RMW time compressed into the kernel tail.
// Change: QUERY-SEQUENTIAL scan — per query: scan 128 pairs -> rescan ->
// atomicMax immediately; order staggered by split (qk=(qs+split)&3) so a
// tile's 16 contenders arrive ~1/4-scan apart. Atomics spread over the
// whole scan; final barrier waits only on the last query's atomic.
// R15 lesson: inline j-tracking = +60% VALU, net +10us — REVERTED to
// R14's group-track + descending rescan (proven absmax 0). Group min via
// pk min2 accumulate + one scalar combine: same exact value (min is
// exact-commutative), 4 fewer instr/group/query than R14.
// R10/R11 lessons kept: NO __threadfence (per-wave L2 wb/inv = ~100us);
// __syncthreads' mandatory vmcnt(0) drains atomics before tid0's counter
// bump; consumers read tab/psum via AGENT-scope atomic loads (sc bypass).
// mktab->fused visibility = kernel boundary (R8-proven). Counter init in
// poisoned ws: CANARY word (never written) holds the fill value; "last"
// test old==canary+(n-1); finalizer restores counters.
// Keys: complemented (score<<32|j), atomicMax; poison/zeros < any real key.

#define BQ      256
#define QPT     4             // queries per thread
#define SPLITS  16
#define CH      256           // refs per split-block
#define GS      8             // refs per tracked group
#define NG      (CH / GS)     // 32 groups
#define BIGOFF  64.0f         // folds into h: scores stay in (64-|q|^2/2, ~200) > 0
#define NQTOT   65536         // 2 dirs * 8 batches * 4096 queries
#define NTILE   64            // query tiles of 1024
#define TILEQ   1024          // queries per tile (BQ * QPT)

typedef float f32x2 __attribute__((ext_vector_type(2)));
typedef float f32x4 __attribute__((ext_vector_type(4)));

static __device__ __forceinline__ f32x2 mk2(float s) { f32x2 v; v.x = s; v.y = s; return v; }
static __device__ __forceinline__ f32x2 fma2(f32x2 a, f32x2 b, f32x2 c) {
    return __builtin_elementwise_fma(a, b, c);
}
static __device__ __forceinline__ f32x2 min2(f32x2 a, f32x2 b) {
    return __builtin_elementwise_min(a, b);
}
__device__ __forceinline__ unsigned int float_ord(float f) {
    unsigned int u = __float_as_uint(f);
    return (u & 0x80000000u) ? ~u : (u | 0x80000000u);
}

// ws layout (fast path):
//   [0,64)      legacy acc area (fallback path only)
//   [128,132)   CANARY u32 — never written; holds the uniform fill value
//   [192,196)   gcnt u32  — global tile-completion counter (starts at canary)
//   [256,512)   tcnt[64] u32 — per-tile split counters (start at canary)
//   [1024,1280) psum[64] f32 — per-tile partial sums
//   [4096, 4096+512K) tab u64[NQTOT] — complemented (score|j) keys, atomicMax
//   [1M, 2M)    tbl f32x4[2 dirs][8 b][2048 pairs][2] — pair-layout ref table
#define WS_ACC    0
#define WS_CANARY 128
#define WS_GCNT   192
#define WS_TCNT   256
#define WS_PSUM   1024
#define WS_TAB    4096
#define WS_TBL    1048576

// ---- phase 0: build the pair-layout (x,x',y,y')(z,z',h,h') ref table.
// 32768 pairs total = 2 dirs * 8 b * 2048 pairs. h chain bit-identical to
// the scan's. Kernel-end release makes it visible to the scan (R8 pattern).
__global__ __launch_bounds__(BQ) void chamfer_mktab(
    const float* __restrict__ x, const float* __restrict__ y,
    float4* __restrict__ tbl)
{
    const int t   = blockIdx.x * BQ + threadIdx.x;   // 0..32767
    const int dir = t >> 14;
    const int b   = (t >> 11) & 7;
    const int pr  = t & 2047;
    const float* R = (dir == 0 ? y : x) + (size_t)b * 4096 * 3;
    const float* rp = R + (size_t)(2 * pr) * 3;
    const float f0 = rp[0], f1 = rp[1], f2 = rp[2];
    const float f3 = rp[3], f4 = rp[4], f5 = rp[5];
    const float h0 = fmaf(0.5f * f0, f0, fmaf(0.5f * f1, f1, fmaf(0.5f * f2, f2, BIGOFF)));
    const float h1 = fmaf(0.5f * f3, f3, fmaf(0.5f * f4, f4, fmaf(0.5f * f5, f5, BIGOFF)));
    const size_t o = ((size_t)(dir * 8 + b) * 2048 + pr) * 2;
    tbl[o]     = make_float4(f0, f3, f1, f4);
    tbl[o + 1] = make_float4(f2, f5, h0, h1);
}

// ---- fused scan + per-tile gather + finalize:
// grid = 64 query-tiles (1024 q each) x 16 ref-splits = 1024 blocks
__global__ __launch_bounds__(BQ, 4) void chamfer_fused_r16(
    const float* __restrict__ x, const float* __restrict__ y,
    const f32x4* __restrict__ tbl,
    unsigned long long* __restrict__ tab,
    unsigned int* __restrict__ tcnt, unsigned int* __restrict__ gcnt,
    const unsigned int* __restrict__ canary_p,
    float* __restrict__ psum, float* __restrict__ out)
{
    __shared__ float red[4];
    __shared__ int s_flag;

    const int bid   = blockIdx.x;
    const int split = bid & (SPLITS - 1);
    const int tq    = bid >> 4;          // 0..63 = dir*32 + b*4 + t4
    const int dir   = tq >> 5;
    const int b     = (tq >> 2) & 7;
    const int t4    = tq & 3;

    const unsigned int canary = *canary_p;  // uniform fill value (0xAA.. or 0)

    const float* Q; const float* R;
    if (dir == 0) { Q = x + (size_t)b * 4096 * 3; R = y + (size_t)b * 4096 * 3; }
    else          { Q = y + (size_t)b * 4096 * 3; R = x + (size_t)b * 4096 * 3; }

    const int tid = threadIdx.x;

    // this block's split region of the table: 128 pairs = 256 f32x4s
    const f32x4* __restrict__ tb =
        tbl + ((size_t)(dir * 8 + b) * 4096 + (size_t)split * 256);

    // preload all 4 queries' negated pk splats (hides the strided Q loads).
    f32x2 nqx[QPT], nqy[QPT], nqz[QPT];
    #pragma unroll
    for (int qk = 0; qk < QPT; ++qk) {
        const int ql = t4 * TILEQ + qk * 256 + tid;
        nqx[qk] = mk2(-Q[ql * 3 + 0]);
        nqy[qk] = mk2(-Q[ql * 3 + 1]);
        nqz[qk] = mk2(-Q[ql * 3 + 2]);
    }

    // ---- QUERY-SEQUENTIAL scan: per query, scan -> rescan -> atomicMax.
    // Order staggered by split so a tile's 16 same-qidx atomics arrive
    // ~1/4-scan apart instead of in one synchronized burst.
    #pragma unroll 1
    for (int qs = 0; qs < QPT; ++qs) {
        const int qk = (qs + split) & (QPT - 1);
        const f32x2 qnx = nqx[qk], qny = nqy[qk], qnz = nqz[qk];

        float best = 3.4e38f; int bg = 0;
        #pragma unroll 4
        for (int g = 0; g < NG; ++g) {
            f32x2 macc = mk2(3.4e38f);
            #pragma unroll
            for (int k4 = 0; k4 < 4; ++k4) {        // 4 ref-pairs per group
                const f32x4 a = tb[(g * 4 + k4) * 2];       // rx0,rx1,ry0,ry1
                const f32x4 c = tb[(g * 4 + k4) * 2 + 1];   // rz0,rz1,h0,h1
                const f32x2 rx = __builtin_shufflevector(a, a, 0, 1);
                const f32x2 ry = __builtin_shufflevector(a, a, 2, 3);
                const f32x2 rz = __builtin_shufflevector(c, c, 0, 1);
                const f32x2 h2 = __builtin_shufflevector(c, c, 2, 3);
                // bit-identical chain: fma(nqx,rx, fma(nqy,ry, fma(nqz,rz,h)))
                const f32x2 s = fma2(qnx, rx, fma2(qny, ry, fma2(qnz, rz, h2)));
                macc = min2(macc, s);               // exact-commutative
            }
            const float m = fminf(macc.x, macc.y);  // same value as R14's chain
            const bool cc = m < best;               // strict <: earliest group
            best = cc ? m : best;
            bg   = cc ? g : bg;
        }

        // exact index: re-scan winning GS-ref group from global R (L2-hot);
        // bit-identical fma/h chain reproduces the packed-path score exactly.
        const float qx = -qnx.x, qy = -qny.x, qz = -qnz.x;
        const int basej = split * CH + bg * GS;
        int bj = basej;
        #pragma unroll
        for (int j = GS - 1; j >= 0; --j) {          // descending: smallest j wins
            const float* rp = R + (size_t)(basej + j) * 3;
            const float rx = rp[0], ry = rp[1], rz = rp[2];
            const float h = fmaf(0.5f * rx, rx, fmaf(0.5f * ry, ry, fmaf(0.5f * rz, rz, BIGOFF)));
            const float s = fmaf(-qx, rx, fmaf(-qy, ry, fmaf(-qz, rz, h)));
            if (s == best) bj = basej + j;
        }

        const size_t qidx = (size_t)tq * TILEQ + qk * 256 + tid;
        // complemented key: max(~packed) == min(packed); 0xAA poison and
        // fresh zeros are both < any real key -> no init required.
        const unsigned long long key =
            ~(((unsigned long long)__float_as_uint(best) << 32) | (unsigned int)bj);
        atomicMax(&tab[qidx], key);   // fire-and-forget, spread in time
    }

    // ---- per-tile completion handshake: 16th split-block gathers the tile.
    // NO __threadfence (R9 lesson: per-wave buffer_wbl2/inv = ~100us).
    // __syncthreads' compiler-mandated s_waitcnt vmcnt(0) drains every
    // wave's atomicMax to the coherent point before tid0's counter bump
    // (only the LAST query's atomic is still in flight here).
    __syncthreads();
    if (tid == 0) {
        const unsigned int old = atomicAdd(&tcnt[tq], 1u);
        s_flag = (old == canary + (SPLITS - 1));
    }
    __syncthreads();
    if (!s_flag) return;

    // ---- gather this tile's 1024 queries (4/thread). tab MUST be read with
    // AGENT-scope atomic loads (sc cache-bypass): local L2 may hold stale
    // poison lines; atomicMax updated the coherent point only (R4 lesson).
    float sthr = 0.0f;
    #pragma unroll
    for (int k = 0; k < QPT; ++k) {
        const int gq = tq * TILEQ + k * 256 + tid;
        const int q  = t4 * TILEQ + k * 256 + tid;
        const unsigned long long w =
            ~__hip_atomic_load(&tab[gq], __ATOMIC_RELAXED, __HIP_MEMORY_SCOPE_AGENT);
        const int j = (int)(unsigned int)w;
        const float dx = Q[q * 3 + 0] - R[(size_t)j * 3 + 0];
        const float dy = Q[q * 3 + 1] - R[(size_t)j * 3 + 1];
        const float dz = Q[q * 3 + 2] - R[(size_t)j * 3 + 2];
        const float ax = fabsf(dx), ay = fabsf(dy), az = fabsf(dz);
        const float ax2 = ax * ax, ay2 = ay * ay, az2 = az * az;
        sthr += ax2 * ax2 * ax + ay2 * ay2 * ay + az2 * az2 * az;
    }
    #pragma unroll
    for (int off = 32; off > 0; off >>= 1) sthr += __shfl_down(sthr, off, 64);
    const int wid = tid >> 6, lane = tid & 63;
    if (lane == 0) red[wid] = sthr;
    __syncthreads();

    if (tid == 0) {
        __hip_atomic_store(&psum[tq], red[0] + red[1] + red[2] + red[3],
                           __ATOMIC_RELAXED, __HIP_MEMORY_SCOPE_AGENT);
        // order psum store before gcnt bump: drain to coherent point (1 instr,
        // single thread — NOT a threadfence, no L2 writeback).
        asm volatile("s_waitcnt vmcnt(0)" ::: "memory");
        const unsigned int old = atomicAdd(gcnt, 1u);
        s_flag = (old == canary + (NTILE - 1));
    }
    __syncthreads();
    if (!s_flag) return;

    // ---- globally-last tile: finalize. x^0.2 via exp2/log2 (rel err ~1e-5).
    // psum read via AGENT-scope bypass loads: counter RMW return proved all
    // writers' stores performed at the coherent point before ours.
    if (tid < 64) {
        float v = 0.0f;
        if (tid < 16) {
            const int fb = tid >> 1, fdir = tid & 1;  // slot = b*2+dir
            float a = 0.0f;
            #pragma unroll
            for (int t = 0; t < 4; ++t)
                a += __hip_atomic_load(&psum[fdir * 32 + fb * 4 + t],
                                       __ATOMIC_RELAXED, __HIP_MEMORY_SCOPE_AGENT);
            v = exp2f(0.2f * log2f(a));
        }
        #pragma unroll
        for (int off = 8; off > 0; off >>= 1) v += __shfl_down(v, off, 64);
        if (tid == 0) out[0] = v * 0.125f;            // mean over B=8
    }
    // restore counters to the canary value so a non-repoisoned rerun is
    // still correct (tab is idempotent under atomicMax with same inputs).
    if (tid < NTILE)
        __hip_atomic_store(&tcnt[tid], canary, __ATOMIC_RELAXED, __HIP_MEMORY_SCOPE_AGENT);
    if (tid == 0)
        __hip_atomic_store(gcnt, canary, __ATOMIC_RELAXED, __HIP_MEMORY_SCOPE_AGENT);
}

// ================= round-2 proven fallback (generic sizes) =================
__global__ __launch_bounds__(BQ) void chamfer_nn_split_kernel(
    const float* __restrict__ x, const float* __restrict__ y,
    unsigned long long* __restrict__ packed, int N, int M)
{
    __shared__ float4 sref[1024];
    const int bid = blockIdx.x, split = bid & 3, qb = bid >> 2;
    const int tile = qb & 15, dir = (qb >> 4) & 1, b = qb >> 5;
    const float* Q; const float* R;
    if (dir == 0) { Q = x + (size_t)b * N * 3; R = y + (size_t)b * M * 3; }
    else          { Q = y + (size_t)b * M * 3; R = x + (size_t)b * N * 3; }
    const int tid = threadIdx.x, q = tile * BQ + tid, base = split * 1024;
    for (int j = tid; j < 1024; j += BQ) {
        const float rx = R[(size_t)(base + j) * 3 + 0];
        const float ry = R[(size_t)(base + j) * 3 + 1];
        const float rz = R[(size_t)(base + j) * 3 + 2];
        sref[j] = make_float4(rx, ry, rz, 0.5f * (rx * rx + ry * ry + rz * rz));
    }
    __syncthreads();
    const float qx = Q[q * 3 + 0], qy = Q[q * 3 + 1], qz = Q[q * 3 + 2];
    float best = 3.4e38f; int bestj = base;
    #pragma unroll 8
    for (int j = 0; j < 1024; ++j) {
        const float4 r = sref[j];
        float t = __fmaf_rn(-qx, r.x, r.w);
        t = __fmaf_rn(-qy, r.y, t);
        t = __fmaf_rn(-qz, r.z, t);
        const bool c = t < best;
        best = c ? t : best; bestj = c ? (base + j) : bestj;
    }
    const size_t idx = ((size_t)dir * 8 + b) * (size_t)N + q;
    atomicMin(&packed[idx], ((unsigned long long)float_ord(best) << 32) | (unsigned int)bestj);
}

__global__ __launch_bounds__(BQ) void chamfer_gather_kernel(
    const float* __restrict__ x, const float* __restrict__ y,
    const unsigned long long* __restrict__ packed,
    float* __restrict__ acc, int N, int M)
{
    __shared__ float red[4];
    const int tid = threadIdx.x;
    const size_t gq = (size_t)blockIdx.x * BQ + tid;
    const int dir = (int)(gq / ((size_t)8 * N));
    const size_t rem = gq - (size_t)dir * 8 * N;
    const int b = (int)(rem / N), q = (int)(rem - (size_t)b * N);
    const float* Q; const float* R;
    if (dir == 0) { Q = x + (size_t)b * N * 3; R = y + (size_t)b * M * 3; }
    else          { Q = y + (size_t)b * M * 3; R = x + (size_t)b * N * 3; }
    const int j = (int)(unsigned int)packed[gq];
    const float dx = Q[q * 3 + 0] - R[(size_t)j * 3 + 0];
    const float dy = Q[q * 3 + 1] - R[(size_t)j * 3 + 1];
    const float dz = Q[q * 3 + 2] - R[(size_t)j * 3 + 2];
    const float ax = fabsf(dx), ay = fabsf(dy), az = fabsf(dz);
    const float ax2 = ax * ax, ay2 = ay * ay, az2 = az * az;
    float s = ax2 * ax2 * ax + ay2 * ay2 * ay + az2 * az2 * az;
    #pragma unroll
    for (int off = 32; off > 0; off >>= 1) s += __shfl_down(s, off, 64);
    const int wid = tid >> 6, lane = tid & 63;
    if (lane == 0) red[wid] = s;
    __syncthreads();
    if (tid == 0) atomicAdd(&acc[b * 2 + dir], red[0] + red[1] + red[2] + red[3]);
}

__global__ void chamfer_finalize_kernel(const float* __restrict__ acc,
                                        float* __restrict__ out)
{
    if (threadIdx.x == 0 && blockIdx.x == 0) {
        float total = 0.0f;
        #pragma unroll
        for (int i = 0; i < 16; ++i) total += powf(acc[i], 0.2f);
        *out = total * 0.125f;
    }
}

extern "C" void kernel_launch(void* const* d_in, const int* in_sizes, int n_in,
                              void* d_out, int out_size, void* d_ws, size_t ws_size,
                              hipStream_t stream)
{
    const float* x = (const float*)d_in[0];
    const float* y = (const float*)d_in[1];
    float* out = (float*)d_out;
    const int N = in_sizes[0] / 24;  // B=8, C=3
    const int M = in_sizes[1] / 24;

    const size_t needed = WS_TBL + (1u << 20);  // table ends at 2MB

    if (N == 4096 && M == 4096 && ws_size >= needed) {
        unsigned char* ws = (unsigned char*)d_ws;
        unsigned long long* tab = (unsigned long long*)(ws + WS_TAB);
        unsigned int* tcnt = (unsigned int*)(ws + WS_TCNT);
        unsigned int* gcnt = (unsigned int*)(ws + WS_GCNT);
        const unsigned int* canary = (const unsigned int*)(ws + WS_CANARY);
        float* psum = (float*)(ws + WS_PSUM);
        chamfer_mktab<<<32768 / BQ, BQ, 0, stream>>>(x, y, (float4*)(ws + WS_TBL));
        chamfer_fused_r16<<<NTILE * SPLITS, BQ, 0, stream>>>(
            x, y, (const f32x4*)(ws + WS_TBL), tab, tcnt, gcnt, canary, psum, out);
    } else {
        // round-2 proven path
        unsigned char* ws = (unsigned char*)d_ws;
        float* acc = (float*)ws;
        unsigned long long* ptab = (unsigned long long*)(ws + 4096);
        const size_t nQ = (size_t)2 * 8 * N;
        hipMemsetAsync(acc, 0, 64, stream);
        hipMemsetAsync(ptab, 0xFF, nQ * 8, stream);
        chamfer_nn_split_kernel<<<(int)(nQ / BQ) * 4, BQ, 0, stream>>>(x, y, ptab, N, M);
        chamfer_gather_kernel<<<(int)(nQ / BQ), BQ, 0, stream>>>(x, y, ptab, acc, N, M);
        chamfer_finalize_kernel<<<1, 64, 0, stream>>>(acc, out);
    }
}

// Round 9
// 88.025 us; speedup vs baseline: 1.1264x; 1.0973x over previous
//
#include <hip/hip_runtime.h>
#include <math.h>

// Chamfer p-norm loss (P=5), B=8, N=M=4096, C=3.
// R17: move the broadcast table reads to the SCALAR pipe.
// Decomposition (R11-R16): scan ~ VALU(19-20us) + stall that tracks the
// COUNT of wave-level broadcast loads: R11 8192 ds_read_b128/CU x12cyc=41us;
// R12 8192 L1 vector loads x ~8cyc data-return = 27us; R14 4096x8=14us.
// Mechanism: a vector load with all 64 lanes at the same address still
// returns 64x16B=1KB/wave through the vector pipe. Broadcast is free only
// on the scalar path: s_load_dwordx16 = 64B ONCE per wave into SGPRs via
// the scalar cache; v_pk_fma_f32 consumes SGPR operands directly (1 SGPR/
// instr rule: chain keeps acc in VGPR; compiler movs h once per pair).
// Also kills the per-load vector address arithmetic (~700 VALU instr/thread
// -> SALU). R16 lesson: query-sequential = 4x table reads, reverted; loads
// shared across all 4 queries again (R14 structure, absmax-0-proven:
// group-track strict-< + descending smallest-j rescan).
// Scalar-cache freshness: mktab -> scan is a dispatch boundary (acquire
// invalidates K$ like it did L1V for R12/R14's vector reads).
// R10/R11 lessons kept: NO __threadfence (per-wave L2 wb/inv = ~100us);
// __syncthreads' mandatory vmcnt(0) drains atomics before tid0's counter
// bump; consumers read tab/psum via AGENT-scope atomic loads (sc bypass).
// Counter init in poisoned ws: CANARY word (never written) holds the fill
// value; "last" test old==canary+(n-1); finalizer restores counters.
// Keys: complemented (score<<32|j), atomicMax; poison/zeros < any real key.

#define BQ      256
#define QPT     4             // queries per thread
#define SPLITS  16
#define CH      256           // refs per split-block
#define GS      8             // refs per tracked group
#define NG      (CH / GS)     // 32 groups
#define BIGOFF  64.0f         // folds into h: scores stay in (64-|q|^2/2, ~200) > 0
#define NQTOT   65536         // 2 dirs * 8 batches * 4096 queries
#define NTILE   64            // query tiles of 1024
#define TILEQ   1024          // queries per tile (BQ * QPT)

typedef float f32x2  __attribute__((ext_vector_type(2)));
typedef float f32x4  __attribute__((ext_vector_type(4)));
typedef float f32x16 __attribute__((ext_vector_type(16)));

static __device__ __forceinline__ f32x2 mk2(float s) { f32x2 v; v.x = s; v.y = s; return v; }
static __device__ __forceinline__ f32x2 fma2(f32x2 a, f32x2 b, f32x2 c) {
    return __builtin_elementwise_fma(a, b, c);
}
static __device__ __forceinline__ f32x2 min2(f32x2 a, f32x2 b) {
    return __builtin_elementwise_min(a, b);
}
__device__ __forceinline__ unsigned int float_ord(float f) {
    unsigned int u = __float_as_uint(f);
    return (u & 0x80000000u) ? ~u : (u | 0x80000000u);
}

// ws layout (fast path):
//   [0,64)      legacy acc area (fallback path only)
//   [128,132)   CANARY u32 — never written; holds the uniform fill value
//   [192,196)   gcnt u32  — global tile-completion counter (starts at canary)
//   [256,512)   tcnt[64] u32 — per-tile split counters (start at canary)
//   [1024,1280) psum[64] f32 — per-tile partial sums
//   [4096, 4096+512K) tab u64[NQTOT] — complemented (score|j) keys, atomicMax
//   [1M, 2M)    tbl f32x4[2 dirs][8 b][2048 pairs][2] — pair-layout ref table
#define WS_ACC    0
#define WS_CANARY 128
#define WS_GCNT   192
#define WS_TCNT   256
#define WS_PSUM   1024
#define WS_TAB    4096
#define WS_TBL    1048576

// ---- phase 0: build the pair-layout (x,x',y,y')(z,z',h,h') ref table.
// 32768 pairs total = 2 dirs * 8 b * 2048 pairs. h chain bit-identical to
// the scan's. Kernel-end release makes it visible to the scan (R8 pattern).
__global__ __launch_bounds__(BQ) void chamfer_mktab(
    const float* __restrict__ x, const float* __restrict__ y,
    float4* __restrict__ tbl)
{
    const int t   = blockIdx.x * BQ + threadIdx.x;   // 0..32767
    const int dir = t >> 14;
    const int b   = (t >> 11) & 7;
    const int pr  = t & 2047;
    const float* R = (dir == 0 ? y : x) + (size_t)b * 4096 * 3;
    const float* rp = R + (size_t)(2 * pr) * 3;
    const float f0 = rp[0], f1 = rp[1], f2 = rp[2];
    const float f3 = rp[3], f4 = rp[4], f5 = rp[5];
    const float h0 = fmaf(0.5f * f0, f0, fmaf(0.5f * f1, f1, fmaf(0.5f * f2, f2, BIGOFF)));
    const float h1 = fmaf(0.5f * f3, f3, fmaf(0.5f * f4, f4, fmaf(0.5f * f5, f5, BIGOFF)));
    const size_t o = ((size_t)(dir * 8 + b) * 2048 + pr) * 2;
    tbl[o]     = make_float4(f0, f3, f1, f4);
    tbl[o + 1] = make_float4(f2, f5, h0, h1);
}

// one ref-pair from an SGPR-resident f32x16 (B = 0 or 8): operands are
// adjacent even-aligned SGPR pairs -> natural 64-bit scalar sources for
// v_pk_fma_f32 (acc stays in VGPR; compiler movs h2 once, shared by 4 qk).
#define PAIR_COMPUTE(W, B)                                               \
  {                                                                      \
    const f32x2 rx = __builtin_shufflevector(W, W, (B) + 0, (B) + 1);    \
    const f32x2 ry = __builtin_shufflevector(W, W, (B) + 2, (B) + 3);    \
    const f32x2 rz = __builtin_shufflevector(W, W, (B) + 4, (B) + 5);    \
    const f32x2 h2 = __builtin_shufflevector(W, W, (B) + 6, (B) + 7);    \
    _Pragma("unroll")                                                    \
    for (int qk = 0; qk < QPT; ++qk) {                                   \
      const f32x2 s = fma2(nqx[qk], rx,                                  \
                      fma2(nqy[qk], ry, fma2(nqz[qk], rz, h2)));         \
      macc[qk] = min2(macc[qk], s);   /* exact-commutative */            \
    }                                                                    \
  }

// ---- fused scan + per-tile gather + finalize:
// grid = 64 query-tiles (1024 q each) x 16 ref-splits = 1024 blocks
__global__ __launch_bounds__(BQ, 4) void chamfer_fused_r17(
    const float* __restrict__ x, const float* __restrict__ y,
    const float* __restrict__ tbl,
    unsigned long long* __restrict__ tab,
    unsigned int* __restrict__ tcnt, unsigned int* __restrict__ gcnt,
    const unsigned int* __restrict__ canary_p,
    float* __restrict__ psum, float* __restrict__ out)
{
    __shared__ float red[4];
    __shared__ int s_flag;

    const int bid   = blockIdx.x;
    const int split = bid & (SPLITS - 1);
    const int tq    = bid >> 4;          // 0..63 = dir*32 + b*4 + t4
    const int dir   = tq >> 5;
    const int b     = (tq >> 2) & 7;
    const int t4    = tq & 3;

    const unsigned int canary = *canary_p;  // uniform fill value (0xAA.. or 0)

    const float* Q; const float* R;
    if (dir == 0) { Q = x + (size_t)b * 4096 * 3; R = y + (size_t)b * 4096 * 3; }
    else          { Q = y + (size_t)b * 4096 * 3; R = x + (size_t)b * 4096 * 3; }

    const int tid = threadIdx.x;

    // this block's split region of the table: 128 pairs * 32B = 4KB
    const float* tb = tbl + ((size_t)(dir * 8 + b) * 16384 + (size_t)split * 1024);

    // 4 scalar queries per thread, kept ONLY as negated pk splats.
    f32x2 nqx[QPT], nqy[QPT], nqz[QPT];
    #pragma unroll
    for (int qk = 0; qk < QPT; ++qk) {
        const int ql = t4 * TILEQ + qk * 256 + tid;
        nqx[qk] = mk2(-Q[ql * 3 + 0]);
        nqy[qk] = mk2(-Q[ql * 3 + 1]);
        nqz[qk] = mk2(-Q[ql * 3 + 2]);
    }

    float best[QPT]; int bg[QPT];
    #pragma unroll
    for (int qk = 0; qk < QPT; ++qk) { best[qk] = 3.4e38f; bg[qk] = 0; }

    // ---- scan: per group, ONE wave-wide scalar fetch of 8 refs (128B)
    // via 2x s_load_dwordx16 into SGPRs; zero vector-memory traffic.
    #pragma unroll 1
    for (int g = 0; g < NG; ++g) {
        f32x16 w0, w1;
        const unsigned int goff = (unsigned int)(g * 128);
        asm("s_load_dwordx16 %0, %2, %3\n\t"
            "s_load_dwordx16 %1, %2, %4\n\t"
            "s_waitcnt lgkmcnt(0)"
            : "=s"(w0), "=s"(w1)
            : "s"(tb), "s"(goff), "s"(goff + 64u));

        f32x2 macc[QPT];
        #pragma unroll
        for (int qk = 0; qk < QPT; ++qk) macc[qk] = mk2(3.4e38f);

        PAIR_COMPUTE(w0, 0)   // pair 4g+0
        PAIR_COMPUTE(w0, 8)   // pair 4g+1
        PAIR_COMPUTE(w1, 0)   // pair 4g+2
        PAIR_COMPUTE(w1, 8)   // pair 4g+3

        #pragma unroll
        for (int qk = 0; qk < QPT; ++qk) {
            const float m = fminf(macc[qk].x, macc[qk].y);  // same value as R14
            const bool cc = m < best[qk];    // strict <: earliest group on ties
            best[qk] = cc ? m : best[qk];
            bg[qk]   = cc ? g : bg[qk];
        }
    }

    // exact index: re-scan winning GS-ref group from global R (L2-hot);
    // bit-identical fma/h chain reproduces the packed-path score exactly.
    #pragma unroll
    for (int qk = 0; qk < QPT; ++qk) {
        const float bscore = best[qk];
        const float qx = -nqx[qk].x;   // bit-exact double sign-flip
        const float qy = -nqy[qk].x;
        const float qz = -nqz[qk].x;
        const int basej = split * CH + bg[qk] * GS;
        int bj = basej;
        #pragma unroll
        for (int j = GS - 1; j >= 0; --j) {      // descending: smallest j wins
            const float* rp = R + (size_t)(basej + j) * 3;
            const float rx = rp[0], ry = rp[1], rz = rp[2];
            const float h = fmaf(0.5f * rx, rx, fmaf(0.5f * ry, ry, fmaf(0.5f * rz, rz, BIGOFF)));
            const float s = fmaf(-qx, rx, fmaf(-qy, ry, fmaf(-qz, rz, h)));
            if (s == bscore) bj = basej + j;
        }
        const size_t qidx = (size_t)tq * TILEQ + qk * 256 + tid;
        // complemented key: max(~packed) == min(packed); 0xAA poison and
        // fresh zeros are both < any real key -> no init required.
        const unsigned long long key =
            ~(((unsigned long long)__float_as_uint(bscore) << 32) | (unsigned int)bj);
        atomicMax(&tab[qidx], key);   // fire-and-forget (return unused)
    }

    // ---- per-tile completion handshake: 16th split-block gathers the tile.
    // NO __threadfence (R9 lesson: per-wave buffer_wbl2/inv = ~100us).
    // __syncthreads' compiler-mandated s_waitcnt vmcnt(0) drains every
    // wave's atomicMax to the coherent point before tid0's counter bump.
    __syncthreads();
    if (tid == 0) {
        const unsigned int old = atomicAdd(&tcnt[tq], 1u);
        s_flag = (old == canary + (SPLITS - 1));
    }
    __syncthreads();
    if (!s_flag) return;

    // ---- gather this tile's 1024 queries (4/thread). tab MUST be read with
    // AGENT-scope atomic loads (sc cache-bypass): local L2 may hold stale
    // poison lines; atomicMax updated the coherent point only (R4 lesson).
    float sthr = 0.0f;
    #pragma unroll
    for (int k = 0; k < QPT; ++k) {
        const int gq = tq * TILEQ + k * 256 + tid;
        const int q  = t4 * TILEQ + k * 256 + tid;
        const unsigned long long w =
            ~__hip_atomic_load(&tab[gq], __ATOMIC_RELAXED, __HIP_MEMORY_SCOPE_AGENT);
        const int j = (int)(unsigned int)w;
        const float dx = Q[q * 3 + 0] - R[(size_t)j * 3 + 0];
        const float dy = Q[q * 3 + 1] - R[(size_t)j * 3 + 1];
        const float dz = Q[q * 3 + 2] - R[(size_t)j * 3 + 2];
        const float ax = fabsf(dx), ay = fabsf(dy), az = fabsf(dz);
        const float ax2 = ax * ax, ay2 = ay * ay, az2 = az * az;
        sthr += ax2 * ax2 * ax + ay2 * ay2 * ay + az2 * az2 * az;
    }
    #pragma unroll
    for (int off = 32; off > 0; off >>= 1) sthr += __shfl_down(sthr, off, 64);
    const int wid = tid >> 6, lane = tid & 63;
    if (lane == 0) red[wid] = sthr;
    __syncthreads();

    if (tid == 0) {
        __hip_atomic_store(&psum[tq], red[0] + red[1] + red[2] + red[3],
                           __ATOMIC_RELAXED, __HIP_MEMORY_SCOPE_AGENT);
        // order psum store before gcnt bump: drain to coherent point (1 instr,
        // single thread — NOT a threadfence, no L2 writeback).
        asm volatile("s_waitcnt vmcnt(0)" ::: "memory");
        const unsigned int old = atomicAdd(gcnt, 1u);
        s_flag = (old == canary + (NTILE - 1));
    }
    __syncthreads();
    if (!s_flag) return;

    // ---- globally-last tile: finalize. x^0.2 via exp2/log2 (rel err ~1e-5).
    // psum read via AGENT-scope bypass loads: counter RMW return proved all
    // writers' stores performed at the coherent point before ours.
    if (tid < 64) {
        float v = 0.0f;
        if (tid < 16) {
            const int fb = tid >> 1, fdir = tid & 1;  // slot = b*2+dir
            float a = 0.0f;
            #pragma unroll
            for (int t = 0; t < 4; ++t)
                a += __hip_atomic_load(&psum[fdir * 32 + fb * 4 + t],
                                       __ATOMIC_RELAXED, __HIP_MEMORY_SCOPE_AGENT);
            v = exp2f(0.2f * log2f(a));
        }
        #pragma unroll
        for (int off = 8; off > 0; off >>= 1) v += __shfl_down(v, off, 64);
        if (tid == 0) out[0] = v * 0.125f;            // mean over B=8
    }
    // restore counters to the canary value so a non-repoisoned rerun is
    // still correct (tab is idempotent under atomicMax with same inputs).
    if (tid < NTILE)
        __hip_atomic_store(&tcnt[tid], canary, __ATOMIC_RELAXED, __HIP_MEMORY_SCOPE_AGENT);
    if (tid == 0)
        __hip_atomic_store(gcnt, canary, __ATOMIC_RELAXED, __HIP_MEMORY_SCOPE_AGENT);
}

// ================= round-2 proven fallback (generic sizes) =================
__global__ __launch_bounds__(BQ) void chamfer_nn_split_kernel(
    const float* __restrict__ x, const float* __restrict__ y,
    unsigned long long* __restrict__ packed, int N, int M)
{
    __shared__ float4 sref[1024];
    const int bid = blockIdx.x, split = bid & 3, qb = bid >> 2;
    const int tile = qb & 15, dir = (qb >> 4) & 1, b = qb >> 5;
    const float* Q; const float* R;
    if (dir == 0) { Q = x + (size_t)b * N * 3; R = y + (size_t)b * M * 3; }
    else          { Q = y + (size_t)b * M * 3; R = x + (size_t)b * N * 3; }
    const int tid = threadIdx.x, q = tile * BQ + tid, base = split * 1024;
    for (int j = tid; j < 1024; j += BQ) {
        const float rx = R[(size_t)(base + j) * 3 + 0];
        const float ry = R[(size_t)(base + j) * 3 + 1];
        const float rz = R[(size_t)(base + j) * 3 + 2];
        sref[j] = make_float4(rx, ry, rz, 0.5f * (rx * rx + ry * ry + rz * rz));
    }
    __syncthreads();
    const float qx = Q[q * 3 + 0], qy = Q[q * 3 + 1], qz = Q[q * 3 + 2];
    float best = 3.4e38f; int bestj = base;
    #pragma unroll 8
    for (int j = 0; j < 1024; ++j) {
        const float4 r = sref[j];
        float t = __fmaf_rn(-qx, r.x, r.w);
        t = __fmaf_rn(-qy, r.y, t);
        t = __fmaf_rn(-qz, r.z, t);
        const bool c = t < best;
        best = c ? t : best; bestj = c ? (base + j) : bestj;
    }
    const size_t idx = ((size_t)dir * 8 + b) * (size_t)N + q;
    atomicMin(&packed[idx], ((unsigned long long)float_ord(best) << 32) | (unsigned int)bestj);
}

__global__ __launch_bounds__(BQ) void chamfer_gather_kernel(
    const float* __restrict__ x, const float* __restrict__ y,
    const unsigned long long* __restrict__ packed,
    float* __restrict__ acc, int N, int M)
{
    __shared__ float red[4];
    const int tid = threadIdx.x;
    const size_t gq = (size_t)blockIdx.x * BQ + tid;
    const int dir = (int)(gq / ((size_t)8 * N));
    const size_t rem = gq - (size_t)dir * 8 * N;
    const int b = (int)(rem / N), q = (int)(rem - (size_t)b * N);
    const float* Q; const float* R;
    if (dir == 0) { Q = x + (size_t)b * N * 3; R = y + (size_t)b * M * 3; }
    else          { Q = y + (size_t)b * M * 3; R = x + (size_t)b * N * 3; }
    const int j = (int)(unsigned int)packed[gq];
    const float dx = Q[q * 3 + 0] - R[(size_t)j * 3 + 0];
    const float dy = Q[q * 3 + 1] - R[(size_t)j * 3 + 1];
    const float dz = Q[q * 3 + 2] - R[(size_t)j * 3 + 2];
    const float ax = fabsf(dx), ay = fabsf(dy), az = fabsf(dz);
    const float ax2 = ax * ax, ay2 = ay * ay, az2 = az * az;
    float s = ax2 * ax2 * ax + ay2 * ay2 * ay + az2 * az2 * az;
    #pragma unroll
    for (int off = 32; off > 0; off >>= 1) s += __shfl_down(s, off, 64);
    const int wid = tid >> 6, lane = tid & 63;
    if (lane == 0) red[wid] = s;
    __syncthreads();
    if (tid == 0) atomicAdd(&acc[b * 2 + dir], red[0] + red[1] + red[2] + red[3]);
}

__global__ void chamfer_finalize_kernel(const float* __restrict__ acc,
                                        float* __restrict__ out)
{
    if (threadIdx.x == 0 && blockIdx.x == 0) {
        float total = 0.0f;
        #pragma unroll
        for (int i = 0; i < 16; ++i) total += powf(acc[i], 0.2f);
        *out = total * 0.125f;
    }
}

extern "C" void kernel_launch(void* const* d_in, const int* in_sizes, int n_in,
                              void* d_out, int out_size, void* d_ws, size_t ws_size,
                              hipStream_t stream)
{
    const float* x = (const float*)d_in[0];
    const float* y = (const float*)d_in[1];
    float* out = (float*)d_out;
    const int N = in_sizes[0] / 24;  // B=8, C=3
    const int M = in_sizes[1] / 24;

    const size_t needed = WS_TBL + (1u << 20);  // table ends at 2MB

    if (N == 4096 && M == 4096 && ws_size >= needed) {
        unsigned char* ws = (unsigned char*)d_ws;
        unsigned long long* tab = (unsigned long long*)(ws + WS_TAB);
        unsigned int* tcnt = (unsigned int*)(ws + WS_TCNT);
        unsigned int* gcnt = (unsigned int*)(ws + WS_GCNT);
        const unsigned int* canary = (const unsigned int*)(ws + WS_CANARY);
        float* psum = (float*)(ws + WS_PSUM);
        chamfer_mktab<<<32768 / BQ, BQ, 0, stream>>>(x, y, (float4*)(ws + WS_TBL));
        chamfer_fused_r17<<<NTILE * SPLITS, BQ, 0, stream>>>(
            x, y, (const float*)(ws + WS_TBL), tab, tcnt, gcnt, canary, psum, out);
    } else {
        // round-2 proven path
        unsigned char* ws = (unsigned char*)d_ws;
        float* acc = (float*)ws;
        unsigned long long* ptab = (unsigned long long*)(ws + 4096);
        const size_t nQ = (size_t)2 * 8 * N;
        hipMemsetAsync(acc, 0, 64, stream);
        hipMemsetAsync(ptab, 0xFF, nQ * 8, stream);
        chamfer_nn_split_kernel<<<(int)(nQ / BQ) * 4, BQ, 0, stream>>>(x, y, ptab, N, M);
        chamfer_gather_kernel<<<(int)(nQ / BQ), BQ, 0, stream>>>(x, y, ptab, acc, N, M);
        chamfer_finalize_kernel<<<1, 64, 0, stream>>>(acc, out);
    }
}